// Round 2
// baseline (400.467 us; speedup 1.0000x reference)
//
#include <hip/hip_runtime.h>
#include <math.h>

#define NBINS 16
#define BOUNDV 3.0f
#define MIN_W 0.001f
#define MIN_H 0.001f
#define MIN_D 0.001f
#define MIN_L 0.025f
#define EPSV 1e-6f

#define TPB 128
#define PPE 63
#define SLABDW (TPB * PPE)        // 8064 dwords per slab (32,256 B)
#define NVEC (SLABDW / 4)         // 2016 float4 per slab
#define TAILV (NVEC - 15 * TPB)   // 96 float4 in the partial 16th pass

__device__ __forceinline__ float frcp(float v) { return __builtin_amdgcn_rcpf(v); }

__device__ __forceinline__ void load_slab(float4* v, const float* __restrict__ params,
                                          int s, int tid) {
    const float4* __restrict__ src = (const float4*)(params + (size_t)s * SLABDW);
    #pragma unroll
    for (int k = 0; k < 15; ++k) v[k] = src[tid + k * TPB];
    if (tid < TAILV) v[15] = src[tid + 15 * TPB];
}

__device__ __forceinline__ void store_slab(float* b, int tid, const float4* v) {
    float4* dst = (float4*)b;
    #pragma unroll
    for (int k = 0; k < 15; ++k) dst[tid + k * TPB] = v[k];
    if (tid < TAILV) dst[tid + 15 * TPB] = v[15];
}

__global__ __launch_bounds__(TPB) void lrs_kernel(
    const float* __restrict__ x_in,
    const float* __restrict__ params,
    float* __restrict__ out,
    int n)
{
    __shared__ __align__(16) float buf0[SLABDW];   // 32,256 B
    __shared__ __align__(16) float buf1[SLABDW];   // -> 64,512 B total, 2 blocks/CU
    const int tid = threadIdx.x;
    const int nslab = n / TPB;                     // 8192
    const int g = gridDim.x;

    int s = blockIdx.x;
    if (s >= nslab) return;

    float4 v[16];
    load_slab(v, params, s, tid);
    float xc = x_in[(size_t)s * TPB + tid];
    store_slab(buf0, tid, v);
    __syncthreads();

    float* cur = buf0;
    float* nxt = buf1;

    for (; s < nslab; s += g) {
        const int sn = s + g;
        const bool hn = (sn < nslab);
        float xn = 0.f;
        if (hn) {
            load_slab(v, params, sn, tid);         // async: in flight during compute below
            xn = x_in[(size_t)sn * TPB + tid];
        }

        // ================= compute element (s, tid) from cur =================
        const float* p = cur + tid * PPE;          // stride 63 (odd) -> 2-way LDS, free
        const float x = xc;

        // softmax over w (p[0..15])
        float wv[NBINS];
        float mw = -1e30f;
        #pragma unroll
        for (int i = 0; i < NBINS; ++i) { wv[i] = p[i]; mw = fmaxf(mw, wv[i]); }
        float sw = 0.f;
        #pragma unroll
        for (int i = 0; i < NBINS; ++i) { wv[i] = __expf(wv[i] - mw); sw += wv[i]; }
        const float invw = frcp(sw);

        // fused cumsum + bin search + width-knot selection
        float cum = 0.f, knp = -BOUNDV, cw = -BOUNDV, cwn = 0.f;
        int bin = 0;
        #pragma unroll
        for (int i = 0; i < NBINS; ++i) {
            cum += fmaf(0.984f, wv[i] * invw, MIN_W);
            float kn = (i == NBINS - 1) ? BOUNDV : fmaf(6.f, cum, -BOUNDV);
            bool hit = (knp + EPSV <= x);
            if (i == 0) { cwn = kn; }
            else if (hit) { bin = i; cw = knp; cwn = kn; }
            knp = kn;
        }

        // issue bin-dependent LDS reads early (hide ~120cy LDS latency under h-softmax)
        const float draw_lo = p[31 + bin];   // raw d[bin-1]  (garbage if bin==0, unused)
        const float draw_hi = p[32 + bin];   // raw d[bin]    (garbage if bin==15, unused)
        const float lraw    = p[47 + bin];   // raw lambda[bin]

        // softmax over h (p[16..31])
        float hv[NBINS];
        float mh = -1e30f;
        #pragma unroll
        for (int i = 0; i < NBINS; ++i) { hv[i] = p[16 + i]; mh = fmaxf(mh, hv[i]); }
        float sh = 0.f;
        #pragma unroll
        for (int i = 0; i < NBINS; ++i) { hv[i] = __expf(hv[i] - mh); sh += hv[i]; }
        const float invh = frcp(sh);

        // height-knot selection
        float cumh = 0.f, khp = -BOUNDV, ya = -BOUNDV, yb = 0.f;
        #pragma unroll
        for (int i = 0; i < NBINS; ++i) {
            cumh += fmaf(0.984f, hv[i] * invh, MIN_H);
            float kh = (i == NBINS - 1) ? BOUNDV : fmaf(6.f, cumh, -BOUNDV);
            if (i == bin) { ya = khp; yb = kh; }
            khp = kh;
        }

        // derivatives (only the two selected; edges are the constant 1-MIN_D)
        const float sp_lo = fmaxf(draw_lo, 0.f) + __logf(1.f + __expf(-fabsf(draw_lo)));
        const float sp_hi = fmaxf(draw_hi, 0.f) + __logf(1.f + __expf(-fabsf(draw_hi)));
        const float d_k  = (bin == 0)         ? (1.f - MIN_D) : (MIN_D + sp_lo);
        const float d_k1 = (bin == NBINS - 1) ? (1.f - MIN_D) : (MIN_D + sp_hi);

        // lambda
        const float sig = frcp(1.f + __expf(-lraw));
        const float lam = fmaf(1.f - 2.f * MIN_L, sig, MIN_L);

        // rational spline
        const float width  = cwn - cw;
        const float height = yb - ya;
        const float inv_w  = frcp(width);
        const float inv_dl = width * frcp(height);          // 1/delta

        const float wb  = __builtin_amdgcn_sqrtf(d_k * frcp(d_k1));
        const float lwb = lam * wb;
        const float wc  = (lam * d_k + (wb - lwb) * d_k1) * inv_dl;
        const float l1  = 1.f - lam;
        const float yc  = (lwb * yb + l1 * ya) * frcp(l1 + lwb);

        const float theta = (x - cw) * inv_w;
        const bool  ind   = (theta <= lam);
        const float lt    = lam - theta;

        const float wcyc  = wc * yc;
        const float wcyct = wcyc * theta;
        const float num   = ind ? fmaf(ya, lt, wcyct)
                                : (wcyc - wcyct) - (wb * yb) * lt;
        const float wct   = wc * theta;
        const float den   = ind ? (wct + lt)
                                : (wc - wct) - wb * lt;
        float outv = num * frcp(den);

        const float dnum = wc * (ind ? lam * (yc - ya) : (wb - lwb) * (yb - yc)) * inv_w;
        float lad = __logf(dnum) - 2.f * __logf(fabsf(den));

        const bool outside = (x < -BOUNDV) | (x > BOUNDV);
        outv = outside ? x   : outv;
        lad  = outside ? 0.f : lad;

        const size_t gid = (size_t)s * TPB + tid;
        out[gid]     = outv;
        out[n + gid] = lad;
        // =====================================================================

        if (hn) store_slab(nxt, tid, v);   // waits vmcnt here (after compute), then barrier
        __syncthreads();
        float* t = cur; cur = nxt; nxt = t;
        xc = xn;
    }
}

extern "C" void kernel_launch(void* const* d_in, const int* in_sizes, int n_in,
                              void* d_out, int out_size, void* d_ws, size_t ws_size,
                              hipStream_t stream) {
    const float* x      = (const float*)d_in[0];
    const float* params = (const float*)d_in[1];
    float* out          = (float*)d_out;
    const int n = in_sizes[0];             // 1,048,576
    const int blocks = 512;                // 2 blocks/CU (LDS: 64,512 B/block), 16 slabs each
    lrs_kernel<<<blocks, TPB, 0, stream>>>(x, params, out, n);
}

// Round 3
// 354.282 us; speedup vs baseline: 1.1304x; 1.1304x over previous
//
#include <hip/hip_runtime.h>
#include <math.h>

#define NBINS 16
#define BOUNDV 3.0f
#define MIN_W 0.001f
#define MIN_H 0.001f
#define MIN_D 0.001f
#define MIN_L 0.025f
#define EPSV 1e-6f

#define TPB 128
#define PPE 63
#define NVEC (TPB * PPE / 4)      // 2016 float4 per slab (32,256 B)

__device__ __forceinline__ float frcp(float v) { return __builtin_amdgcn_rcpf(v); }

// HBM -> LDS direct DMA, 16B per lane. lptr must be wave-uniform (chunk base);
// HW writes lane i at lptr + i*16.
#define GLOAD_LDS16(gp, lp)                                             \
    __builtin_amdgcn_global_load_lds(                                   \
        (const __attribute__((address_space(1))) void*)(gp),            \
        (__attribute__((address_space(3))) void*)(lp), 16, 0, 0)

__global__ __launch_bounds__(TPB) void lrs_kernel(
    const float* __restrict__ x_in,
    const float* __restrict__ params,
    float* __restrict__ out,
    int n)
{
    __shared__ __align__(16) float4 slab[NVEC];   // 32,256 B -> 5 blocks/CU, 10 waves/CU
    const int tid = threadIdx.x;
    const size_t gid = (size_t)blockIdx.x * TPB + tid;

    const float x = x_in[gid];

    // ---- stage slab via global_load_lds (all 16 loads in flight per wave) ----
    {
        const float4* __restrict__ src =
            (const float4*)(params + (size_t)blockIdx.x * (TPB * PPE));
        #pragma unroll
        for (int k = 0; k < 15; ++k) {
            const int j = k * TPB + tid;
            GLOAD_LDS16(src + j, &slab[j & ~63]);
        }
        const int j = 15 * TPB + tid;                 // tail: 96 of 128 lanes
        if (j < NVEC) GLOAD_LDS16(src + j, &slab[j & ~63]);
    }
    __syncthreads();   // s_waitcnt vmcnt(0) + barrier drains the DMA

    const float* p = (const float*)slab + tid * PPE;  // stride 63 (odd): conflict-free

    // ---- softmax over w (p[0..15]) ----
    float wv[NBINS];
    float mw = -1e30f;
    #pragma unroll
    for (int i = 0; i < NBINS; ++i) { wv[i] = p[i]; mw = fmaxf(mw, wv[i]); }
    float sw = 0.f;
    #pragma unroll
    for (int i = 0; i < NBINS; ++i) { wv[i] = __expf(wv[i] - mw); sw += wv[i]; }
    const float invw = frcp(sw);

    // ---- fused cumsum + bin search + width-knot selection ----
    float cum = 0.f, knp = -BOUNDV, cw = -BOUNDV, cwn = 0.f;
    int bin = 0;
    #pragma unroll
    for (int i = 0; i < NBINS; ++i) {
        cum += fmaf(0.984f, wv[i] * invw, MIN_W);
        float kn = (i == NBINS - 1) ? BOUNDV : fmaf(6.f, cum, -BOUNDV);
        bool hit = (knp + EPSV <= x);
        if (i == 0) { cwn = kn; }
        else if (hit) { bin = i; cw = knp; cwn = kn; }
        knp = kn;
    }

    // bin-dependent LDS reads issued early (latency hidden under h-softmax)
    const float draw_lo = p[31 + bin];   // raw d[bin-1]  (unused if bin==0)
    const float draw_hi = p[32 + bin];   // raw d[bin]    (unused if bin==15)
    const float lraw    = p[47 + bin];   // raw lambda[bin]

    // ---- softmax over h (p[16..31]) ----
    float hv[NBINS];
    float mh = -1e30f;
    #pragma unroll
    for (int i = 0; i < NBINS; ++i) { hv[i] = p[16 + i]; mh = fmaxf(mh, hv[i]); }
    float sh = 0.f;
    #pragma unroll
    for (int i = 0; i < NBINS; ++i) { hv[i] = __expf(hv[i] - mh); sh += hv[i]; }
    const float invh = frcp(sh);

    // ---- height-knot selection ----
    float cumh = 0.f, khp = -BOUNDV, ya = -BOUNDV, yb = 0.f;
    #pragma unroll
    for (int i = 0; i < NBINS; ++i) {
        cumh += fmaf(0.984f, hv[i] * invh, MIN_H);
        float kh = (i == NBINS - 1) ? BOUNDV : fmaf(6.f, cumh, -BOUNDV);
        if (i == bin) { ya = khp; yb = kh; }
        khp = kh;
    }

    // ---- derivatives: only the two selected (edges are the constant 1-MIN_D) ----
    const float sp_lo = fmaxf(draw_lo, 0.f) + __logf(1.f + __expf(-fabsf(draw_lo)));
    const float sp_hi = fmaxf(draw_hi, 0.f) + __logf(1.f + __expf(-fabsf(draw_hi)));
    const float d_k  = (bin == 0)         ? (1.f - MIN_D) : (MIN_D + sp_lo);
    const float d_k1 = (bin == NBINS - 1) ? (1.f - MIN_D) : (MIN_D + sp_hi);

    // ---- lambda ----
    const float sig = frcp(1.f + __expf(-lraw));
    const float lam = fmaf(1.f - 2.f * MIN_L, sig, MIN_L);

    // ---- rational spline ----
    const float width  = cwn - cw;
    const float height = yb - ya;
    const float inv_w  = frcp(width);
    const float inv_dl = width * frcp(height);          // 1/delta

    const float wb  = __builtin_amdgcn_sqrtf(d_k * frcp(d_k1));
    const float lwb = lam * wb;
    const float wc  = (lam * d_k + (wb - lwb) * d_k1) * inv_dl;
    const float l1  = 1.f - lam;
    const float yc  = (lwb * yb + l1 * ya) * frcp(l1 + lwb);

    const float theta = (x - cw) * inv_w;
    const bool  ind   = (theta <= lam);
    const float lt    = lam - theta;

    const float wcyc  = wc * yc;
    const float wcyct = wcyc * theta;
    const float num   = ind ? fmaf(ya, lt, wcyct)
                            : (wcyc - wcyct) - (wb * yb) * lt;
    const float wct   = wc * theta;
    const float den   = ind ? (wct + lt)
                            : (wc - wct) - wb * lt;
    float outv = num * frcp(den);

    const float dnum = wc * (ind ? lam * (yc - ya) : (wb - lwb) * (yb - yc)) * inv_w;
    float lad = __logf(dnum) - 2.f * __logf(fabsf(den));

    const bool outside = (x < -BOUNDV) | (x > BOUNDV);
    outv = outside ? x   : outv;
    lad  = outside ? 0.f : lad;

    out[gid]     = outv;
    out[n + gid] = lad;
}

extern "C" void kernel_launch(void* const* d_in, const int* in_sizes, int n_in,
                              void* d_out, int out_size, void* d_ws, size_t ws_size,
                              hipStream_t stream) {
    const float* x      = (const float*)d_in[0];
    const float* params = (const float*)d_in[1];
    float* out          = (float*)d_out;
    const int n = in_sizes[0];            // 1,048,576
    const int blocks = n / TPB;           // 8192
    lrs_kernel<<<blocks, TPB, 0, stream>>>(x, params, out, n);
}